// Round 3
// baseline (212.886 us; speedup 1.0000x reference)
//
#include <hip/hip_runtime.h>
#include <cstdint>
#include <cstddef>

#define B 128
#define P 8732
#define NC 21
#define O 16
#define THRESH 0.5f
#define TILE 256

typedef unsigned long long u64;
typedef unsigned int u32;

__device__ __forceinline__ float iou_pt(float a0, float a1, float a2, float a3,
                                        float b0, float b1, float b2, float b3) {
    float ltx = fmaxf(a0, b0), lty = fmaxf(a1, b1);
    float rbx = fminf(a2, b2), rby = fminf(a3, b3);
    float wx = fmaxf(rbx - ltx, 0.0f), wy = fmaxf(rby - lty, 0.0f);
    float inter = wx * wy;
    float aa = (a2 - a0) * (a3 - a1);
    float ab = (b2 - b0) * (b3 - b1);
    return inter / (aa + ab - inter);
}

// Pass 1: per-object best prior (argmax over p, first occurrence on tie).
__global__ void __launch_bounds__(256) k_pass1(const float* __restrict__ gt,
                                               const float* __restrict__ priors,
                                               u64* __restrict__ bestkey) {
    const int b = blockIdx.y;
    __shared__ float s_gt[O * 4];
    __shared__ u64 s_wk[4][O];
    const int tid = threadIdx.x;
    const int wave = tid >> 6;
    const int lane = tid & 63;
    if (tid < O * 4) {
        int o = tid >> 2, c = tid & 3;
        s_gt[tid] = gt[(b * O + o) * 5 + c];
    }
    __syncthreads();

    u64 lk[O];
#pragma unroll
    for (int o = 0; o < O; o++) lk[o] = 0ull;

    const int stride = gridDim.x * blockDim.x;
    for (int p = blockIdx.x * blockDim.x + tid; p < P; p += stride) {
        float4 pr = reinterpret_cast<const float4*>(priors)[p];
        float b0 = pr.x - pr.z * 0.5f, b1 = pr.y - pr.w * 0.5f;
        float b2 = pr.x + pr.z * 0.5f, b3 = pr.y + pr.w * 0.5f;
#pragma unroll
        for (int o = 0; o < O; o++) {
            float v = iou_pt(s_gt[o * 4 + 0], s_gt[o * 4 + 1], s_gt[o * 4 + 2], s_gt[o * 4 + 3],
                             b0, b1, b2, b3);
            u64 key = ((u64)__float_as_uint(v) << 32) | (u64)(0xFFFFFFFFu - (u32)p);
            lk[o] = (key > lk[o]) ? key : lk[o];
        }
    }

#pragma unroll
    for (int o = 0; o < O; o++) {
        u64 k = lk[o];
#pragma unroll
        for (int off = 32; off > 0; off >>= 1) {
            u64 other = (u64)__shfl_xor((long long)k, off, 64);
            k = (other > k) ? other : k;
        }
        if (lane == 0) s_wk[wave][o] = k;
    }
    __syncthreads();
    if (tid < O) {
        u64 k = s_wk[0][tid];
#pragma unroll
        for (int w = 1; w < 4; w++) { u64 v = s_wk[w][tid]; k = (v > k) ? v : k; }
        atomicMax(&bestkey[b * O + tid], k);
    }
}

// Pass 2: tiled by 256 contiguous priors; scores staged to LDS via coalesced float4.
__global__ void __launch_bounds__(256) k_pass2(const float* __restrict__ gt,
                                               const float* __restrict__ priors,
                                               const u64* __restrict__ bestkey,
                                               const float* __restrict__ loc_preds,
                                               const float* __restrict__ scores,
                                               float* __restrict__ mine,
                                               int* __restrict__ num_pos,
                                               u32* __restrict__ total_pos,
                                               double* __restrict__ acc) {
    const int b = blockIdx.y;
    const int p0 = blockIdx.x * TILE;
    const int n = (P - p0 < TILE) ? (P - p0) : TILE;
    const int tid = threadIdx.x;

    __shared__ float s_sc[TILE * NC];   // 21504 B
    __shared__ float s_gt[O * 5];
    __shared__ int s_bp[O];

    if (tid < O * 5) s_gt[tid] = gt[b * O * 5 + tid];
    if (tid < O) s_bp[tid] = (int)(0xFFFFFFFFu - (u32)(bestkey[b * O + tid] & 0xFFFFFFFFull));

    // coalesced float4 staging of the score slab (n*21 floats; divisible by 4
    // for both full tiles (256*21) and the tail tile (28*21=588))
    {
        const float4* src = reinterpret_cast<const float4*>(scores + ((size_t)b * P + p0) * NC);
        float4* dst = reinterpret_cast<float4*>(s_sc);
        const int nf4 = n * NC / 4;
        for (int i = tid; i < nf4; i += TILE) dst[i] = src[i];
    }
    __syncthreads();

    double l_loc = 0.0, l_ce = 0.0;
    int l_np = 0;

    if (tid < n) {
        const int p = p0 + tid;
        float4 pr = reinterpret_cast<const float4*>(priors)[p];
        float pb0 = pr.x - pr.z * 0.5f, pb1 = pr.y - pr.w * 0.5f;
        float pb2 = pr.x + pr.z * 0.5f, pb3 = pr.y + pr.w * 0.5f;

        float best_ov = -1.0f;
        int best_idx = 0;
#pragma unroll
        for (int o = 0; o < O; o++) {
            float v = iou_pt(s_gt[o * 5 + 0], s_gt[o * 5 + 1], s_gt[o * 5 + 2], s_gt[o * 5 + 3],
                             pb0, pb1, pb2, pb3);
            if (v > best_ov) { best_ov = v; best_idx = o; }
        }
#pragma unroll
        for (int o = 0; o < O; o++) {
            if (s_bp[o] == p) { best_idx = o; best_ov = 2.0f; }
        }
        int cls = (best_ov < THRESH) ? 0 : (int)s_gt[best_idx * 5 + 4];

        const float* sv = s_sc + tid * NC;   // stride 21: coprime to 32 banks
        float mx = sv[0];
#pragma unroll
        for (int c = 1; c < NC; c++) mx = fmaxf(mx, sv[c]);
        float se = 0.0f;
#pragma unroll
        for (int c = 0; c < NC; c++) se += expf(sv[c] - mx);
        float lse = mx + logf(se);
        float ce = lse - sv[cls];

        bool pos = cls > 0;
        mine[(size_t)b * P + p] = pos ? 0.0f : ce;

        if (pos) {
            l_np = 1;
            l_ce = (double)ce;
            float m0 = s_gt[best_idx * 5 + 0], m1 = s_gt[best_idx * 5 + 1];
            float m2 = s_gt[best_idx * 5 + 2], m3 = s_gt[best_idx * 5 + 3];
            float tx = ((m0 + m2) * 0.5f - pr.x) / (0.1f * pr.z);
            float ty = ((m1 + m3) * 0.5f - pr.y) / (0.1f * pr.w);
            float tw = logf((m2 - m0) / pr.z) / 0.2f;
            float th = logf((m3 - m1) / pr.w) / 0.2f;
            float4 lp = reinterpret_cast<const float4*>(loc_preds)[(size_t)b * P + p];
            float d0 = fabsf(lp.x - tx), d1 = fabsf(lp.y - ty);
            float d2 = fabsf(lp.z - tw), d3 = fabsf(lp.w - th);
            float s0 = d0 < 1.0f ? 0.5f * d0 * d0 : d0 - 0.5f;
            float s1 = d1 < 1.0f ? 0.5f * d1 * d1 : d1 - 0.5f;
            float s2 = d2 < 1.0f ? 0.5f * d2 * d2 : d2 - 0.5f;
            float s3 = d3 < 1.0f ? 0.5f * d3 * d3 : d3 - 0.5f;
            l_loc = (double)(s0 + s1 + s2 + s3);
        }
    }

    // wave shuffle reductions, then one atomic per block
    const int lane = tid & 63;
    const int wave = tid >> 6;
#pragma unroll
    for (int off = 32; off > 0; off >>= 1) {
        l_loc += __shfl_xor(l_loc, off, 64);
        l_ce  += __shfl_xor(l_ce, off, 64);
        l_np  += __shfl_xor(l_np, off, 64);
    }
    __shared__ double s_loc[4], s_ce[4];
    __shared__ int s_np[4];
    if (lane == 0) { s_loc[wave] = l_loc; s_ce[wave] = l_ce; s_np[wave] = l_np; }
    __syncthreads();
    if (tid == 0) {
        double t_loc = s_loc[0] + s_loc[1] + s_loc[2] + s_loc[3];
        double t_ce  = s_ce[0] + s_ce[1] + s_ce[2] + s_ce[3];
        int t_np = s_np[0] + s_np[1] + s_np[2] + s_np[3];
        atomicAdd(&acc[0], t_loc);
        atomicAdd(&acc[1], t_ce);
        atomicAdd(&num_pos[b], t_np);
        atomicAdd(total_pos, (u32)t_np);
    }
}

// Top-k sum of mine[b,:] via 4-pass radix select on float bits (all values >= 0)
__global__ void __launch_bounds__(512) k_hardneg(const float* __restrict__ mine,
                                                 const int* __restrict__ num_pos,
                                                 const u32* __restrict__ total_pos,
                                                 double* __restrict__ acc) {
    const int b = blockIdx.x;
    const int tp = (int)*total_pos;
    const int np = num_pos[b];
    int k = 3 * np;
    int cap = P - tp - 1;
    if (cap < k) k = cap;
    if (k <= 0) return;

    __shared__ float s_mine[P];
    __shared__ u32 s_hist[256];
    __shared__ u32 s_state[3];
    const int tid = threadIdx.x;

    for (int i = tid; i < P; i += blockDim.x) s_mine[i] = mine[(size_t)b * P + i];
    if (tid == 0) { s_state[0] = 0u; s_state[1] = (u32)k; s_state[2] = 0u; }
    __syncthreads();

    for (int shift = 24; shift >= 0; shift -= 8) {
        for (int i = tid; i < 256; i += blockDim.x) s_hist[i] = 0u;
        __syncthreads();
        u32 prefix = s_state[0];
        u32 himask = (shift == 24) ? 0u : (0xFFFFFFFFu << (shift + 8));
        for (int i = tid; i < P; i += blockDim.x) {
            u32 v = __float_as_uint(s_mine[i]);
            if ((v & himask) == prefix) atomicAdd(&s_hist[(v >> shift) & 255u], 1u);
        }
        __syncthreads();
        if (tid == 0) {
            u32 kr = s_state[1];
            u32 c = 0;
            int chosen = 0;
            for (int j = 255; j >= 0; j--) {
                u32 nc = c + s_hist[j];
                if (nc >= kr) { chosen = j; break; }
                c = nc;
            }
            s_state[0] = prefix | ((u32)chosen << shift);
            s_state[1] = kr - c;
            s_state[2] += c;
        }
        __syncthreads();
    }

    u32 tbits = s_state[0];
    u32 kr = s_state[1];
    float T = __uint_as_float(tbits);

    double s = 0.0;
    for (int i = tid; i < P; i += blockDim.x) {
        u32 v = __float_as_uint(s_mine[i]);
        if (v > tbits) s += (double)s_mine[i];
    }
    const int lane = tid & 63;
    const int wave = tid >> 6;
#pragma unroll
    for (int off = 32; off > 0; off >>= 1) s += __shfl_xor(s, off, 64);
    __shared__ double s_red[8];
    if (lane == 0) s_red[wave] = s;
    __syncthreads();
    if (tid == 0) {
        double t = 0.0;
        for (int w = 0; w < 8; w++) t += s_red[w];
        atomicAdd(&acc[2], t + (double)kr * (double)T);
    }
}

__global__ void k_finalize(const double* __restrict__ acc,
                           const u32* __restrict__ total_pos,
                           float* __restrict__ out) {
    double n = (double)(*total_pos);
    out[0] = (float)(acc[0] / n);
    out[1] = (float)((acc[1] + acc[2]) / n);
}

extern "C" void kernel_launch(void* const* d_in, const int* in_sizes, int n_in,
                              void* d_out, int out_size, void* d_ws, size_t ws_size,
                              hipStream_t stream) {
    const float* loc_preds = (const float*)d_in[0];
    const float* scores    = (const float*)d_in[1];
    const float* gt        = (const float*)d_in[2];
    const float* priors    = (const float*)d_in[3];

    char* ws = (char*)d_ws;
    double* acc      = (double*)ws;
    u32* total_pos   = (u32*)(ws + 24);
    int* num_pos     = (int*)(ws + 32);
    u64* bestkey     = (u64*)(ws + 544);
    float* mine      = (float*)(ws + 16960);

    hipMemsetAsync(d_ws, 0, 16928, stream);

    k_pass1<<<dim3(8, B), dim3(256), 0, stream>>>(gt, priors, bestkey);
    k_pass2<<<dim3((P + TILE - 1) / TILE, B), dim3(256), 0, stream>>>(
        gt, priors, bestkey, loc_preds, scores, mine, num_pos, total_pos, acc);
    k_hardneg<<<dim3(B), dim3(512), 0, stream>>>(mine, num_pos, total_pos, acc);
    k_finalize<<<1, 1, 0, stream>>>(acc, total_pos, (float*)d_out);
}

// Round 4
// 99.801 us; speedup vs baseline: 2.1331x; 2.1331x over previous
//
#include <hip/hip_runtime.h>
#include <cstdint>
#include <cstddef>

#define B 128
#define P 8732
#define NC 21
#define O 16
#define THRESH 0.5f
#define QPI 2183   // quads per image = P/4

typedef unsigned long long u64;
typedef unsigned int u32;

__device__ __forceinline__ float iou_pt(float a0, float a1, float a2, float a3,
                                        float b0, float b1, float b2, float b3) {
    float ltx = fmaxf(a0, b0), lty = fmaxf(a1, b1);
    float rbx = fminf(a2, b2), rby = fminf(a3, b3);
    float wx = fmaxf(rbx - ltx, 0.0f), wy = fmaxf(rby - lty, 0.0f);
    float inter = wx * wy;
    float aa = (a2 - a0) * (a3 - a1);
    float ab = (b2 - b0) * (b3 - b1);
    return inter / (aa + ab - inter);
}

// Pass 1: per-object best prior (argmax over p, first occurrence on tie).
__global__ void __launch_bounds__(256) k_pass1(const float* __restrict__ gt,
                                               const float* __restrict__ priors,
                                               u64* __restrict__ bestkey) {
    const int b = blockIdx.y;
    __shared__ float s_gt[O * 4];
    __shared__ u64 s_wk[4][O];
    const int tid = threadIdx.x;
    const int wave = tid >> 6;
    const int lane = tid & 63;
    if (tid < O * 4) {
        int o = tid >> 2, c = tid & 3;
        s_gt[tid] = gt[(b * O + o) * 5 + c];
    }
    __syncthreads();

    u64 lk[O];
#pragma unroll
    for (int o = 0; o < O; o++) lk[o] = 0ull;

    const int stride = gridDim.x * blockDim.x;
    for (int p = blockIdx.x * blockDim.x + tid; p < P; p += stride) {
        float4 pr = reinterpret_cast<const float4*>(priors)[p];
        float b0 = pr.x - pr.z * 0.5f, b1 = pr.y - pr.w * 0.5f;
        float b2 = pr.x + pr.z * 0.5f, b3 = pr.y + pr.w * 0.5f;
#pragma unroll
        for (int o = 0; o < O; o++) {
            float v = iou_pt(s_gt[o * 4 + 0], s_gt[o * 4 + 1], s_gt[o * 4 + 2], s_gt[o * 4 + 3],
                             b0, b1, b2, b3);
            u64 key = ((u64)__float_as_uint(v) << 32) | (u64)(0xFFFFFFFFu - (u32)p);
            lk[o] = (key > lk[o]) ? key : lk[o];
        }
    }

#pragma unroll
    for (int o = 0; o < O; o++) {
        u64 k = lk[o];
#pragma unroll
        for (int off = 32; off > 0; off >>= 1) {
            u64 other = (u64)__shfl_xor((long long)k, off, 64);
            k = (other > k) ? other : k;
        }
        if (lane == 0) s_wk[wave][o] = k;
    }
    __syncthreads();
    if (tid < O) {
        u64 k = s_wk[0][tid];
#pragma unroll
        for (int w = 1; w < 4; w++) { u64 v = s_wk[w][tid]; k = (v > k) ? v : k; }
        atomicMax(&bestkey[b * O + tid], k);
    }
}

// Pass 2: 4 priors/thread, 21 independent float4 score loads straight to
// registers (max MLP, no LDS round-trip), hardware exp2/log transcendentals.
__global__ void __launch_bounds__(256) k_pass2(const float* __restrict__ gt,
                                               const float* __restrict__ priors,
                                               const u64* __restrict__ bestkey,
                                               const float* __restrict__ loc_preds,
                                               const float* __restrict__ scores,
                                               float* __restrict__ mine,
                                               int* __restrict__ num_pos,
                                               u32* __restrict__ total_pos,
                                               double* __restrict__ acc) {
    const int b = blockIdx.y;
    __shared__ float s_gt[O * 5];
    __shared__ int s_bp[O];
    const int tid = threadIdx.x;
    if (tid < O * 5) s_gt[tid] = gt[b * O * 5 + tid];
    if (tid < O) s_bp[tid] = (int)(0xFFFFFFFFu - (u32)(bestkey[b * O + tid] & 0xFFFFFFFFull));
    __syncthreads();

    const int gq = blockIdx.x * 256 + tid;  // quad index within image
    double l_loc = 0.0, l_ce = 0.0;
    int l_np = 0;

    if (gq < QPI) {
        const int p0 = gq * 4;
        // 21 independent, contiguous, 16B-aligned loads -> all in flight at once
        float fs[84];
        const float4* s4 = reinterpret_cast<const float4*>(scores)
                           + (size_t)b * (size_t)(P * NC / 4) + (size_t)21 * gq;
#pragma unroll
        for (int i = 0; i < 21; i++) {
            float4 v = s4[i];
            fs[4 * i + 0] = v.x; fs[4 * i + 1] = v.y;
            fs[4 * i + 2] = v.z; fs[4 * i + 3] = v.w;
        }
        float4 pr4[4];
#pragma unroll
        for (int j = 0; j < 4; j++) pr4[j] = reinterpret_cast<const float4*>(priors)[p0 + j];

        float mine_v[4];

#pragma unroll
        for (int j = 0; j < 4; j++) {
            const int p = p0 + j;
            const float4 pr = pr4[j];
            float pb0 = pr.x - pr.z * 0.5f, pb1 = pr.y - pr.w * 0.5f;
            float pb2 = pr.x + pr.z * 0.5f, pb3 = pr.y + pr.w * 0.5f;

            float best_ov = -1.0f;
            int best_idx = 0;
#pragma unroll
            for (int o = 0; o < O; o++) {
                float v = iou_pt(s_gt[o * 5 + 0], s_gt[o * 5 + 1], s_gt[o * 5 + 2], s_gt[o * 5 + 3],
                                 pb0, pb1, pb2, pb3);
                if (v > best_ov) { best_ov = v; best_idx = o; }
            }
#pragma unroll
            for (int o = 0; o < O; o++) {
                if (s_bp[o] == p) { best_idx = o; best_ov = 2.0f; }
            }
            int cls = (best_ov < THRESH) ? 0 : (int)s_gt[best_idx * 5 + 4];

            float mx = fs[21 * j];
#pragma unroll
            for (int c = 1; c < NC; c++) mx = fmaxf(mx, fs[21 * j + c]);
            float se = 0.0f;
#pragma unroll
            for (int c = 0; c < NC; c++) se += __expf(fs[21 * j + c] - mx);
            float lse = mx + __logf(se);
            // gather fs[21j+cls] without runtime indexing (keeps array in VGPRs)
            float g = fs[21 * j];
#pragma unroll
            for (int c = 1; c < NC; c++) g = (c == cls) ? fs[21 * j + c] : g;
            float ce = lse - g;

            bool pos = cls > 0;
            mine_v[j] = pos ? 0.0f : ce;

            if (pos) {
                l_np++;
                l_ce += (double)ce;
                float m0 = s_gt[best_idx * 5 + 0], m1 = s_gt[best_idx * 5 + 1];
                float m2 = s_gt[best_idx * 5 + 2], m3 = s_gt[best_idx * 5 + 3];
                float tx = ((m0 + m2) * 0.5f - pr.x) / (0.1f * pr.z);
                float ty = ((m1 + m3) * 0.5f - pr.y) / (0.1f * pr.w);
                float tw = __logf((m2 - m0) / pr.z) * 5.0f;   // /0.2
                float th = __logf((m3 - m1) / pr.w) * 5.0f;
                float4 lp = reinterpret_cast<const float4*>(loc_preds)[(size_t)b * P + p];
                float d0 = fabsf(lp.x - tx), d1 = fabsf(lp.y - ty);
                float d2 = fabsf(lp.z - tw), d3 = fabsf(lp.w - th);
                float s0 = d0 < 1.0f ? 0.5f * d0 * d0 : d0 - 0.5f;
                float s1 = d1 < 1.0f ? 0.5f * d1 * d1 : d1 - 0.5f;
                float s2 = d2 < 1.0f ? 0.5f * d2 * d2 : d2 - 0.5f;
                float s3 = d3 < 1.0f ? 0.5f * d3 * d3 : d3 - 0.5f;
                l_loc += (double)(s0 + s1 + s2 + s3);
            }
        }
        float4 mv = make_float4(mine_v[0], mine_v[1], mine_v[2], mine_v[3]);
        reinterpret_cast<float4*>(mine)[((size_t)b * P + p0) >> 2] = mv;
    }

    // wave shuffle reductions, then one atomic per block
    const int lane = tid & 63;
    const int wave = tid >> 6;
#pragma unroll
    for (int off = 32; off > 0; off >>= 1) {
        l_loc += __shfl_xor(l_loc, off, 64);
        l_ce  += __shfl_xor(l_ce, off, 64);
        l_np  += __shfl_xor(l_np, off, 64);
    }
    __shared__ double s_loc[4], s_ce[4];
    __shared__ int s_np[4];
    if (lane == 0) { s_loc[wave] = l_loc; s_ce[wave] = l_ce; s_np[wave] = l_np; }
    __syncthreads();
    if (tid == 0) {
        double t_loc = s_loc[0] + s_loc[1] + s_loc[2] + s_loc[3];
        double t_ce  = s_ce[0] + s_ce[1] + s_ce[2] + s_ce[3];
        int t_np = s_np[0] + s_np[1] + s_np[2] + s_np[3];
        atomicAdd(&acc[0], t_loc);
        atomicAdd(&acc[1], t_ce);
        atomicAdd(&num_pos[b], t_np);
        atomicAdd(total_pos, (u32)t_np);
    }
}

// Top-k sum of mine[b,:] via 4-pass radix select on float bits (all values >= 0)
__global__ void __launch_bounds__(512) k_hardneg(const float* __restrict__ mine,
                                                 const int* __restrict__ num_pos,
                                                 const u32* __restrict__ total_pos,
                                                 double* __restrict__ acc) {
    const int b = blockIdx.x;
    const int tp = (int)*total_pos;
    const int np = num_pos[b];
    int k = 3 * np;
    int cap = P - tp - 1;
    if (cap < k) k = cap;
    if (k <= 0) return;

    __shared__ float s_mine[P];
    __shared__ u32 s_hist[256];
    __shared__ u32 s_state[3];
    const int tid = threadIdx.x;

    for (int i = tid; i < P; i += blockDim.x) s_mine[i] = mine[(size_t)b * P + i];
    if (tid == 0) { s_state[0] = 0u; s_state[1] = (u32)k; s_state[2] = 0u; }
    __syncthreads();

    for (int shift = 24; shift >= 0; shift -= 8) {
        for (int i = tid; i < 256; i += blockDim.x) s_hist[i] = 0u;
        __syncthreads();
        u32 prefix = s_state[0];
        u32 himask = (shift == 24) ? 0u : (0xFFFFFFFFu << (shift + 8));
        for (int i = tid; i < P; i += blockDim.x) {
            u32 v = __float_as_uint(s_mine[i]);
            if ((v & himask) == prefix) atomicAdd(&s_hist[(v >> shift) & 255u], 1u);
        }
        __syncthreads();
        if (tid == 0) {
            u32 kr = s_state[1];
            u32 c = 0;
            int chosen = 0;
            for (int j = 255; j >= 0; j--) {
                u32 nc = c + s_hist[j];
                if (nc >= kr) { chosen = j; break; }
                c = nc;
            }
            s_state[0] = prefix | ((u32)chosen << shift);
            s_state[1] = kr - c;
            s_state[2] += c;
        }
        __syncthreads();
    }

    u32 tbits = s_state[0];
    u32 kr = s_state[1];
    float T = __uint_as_float(tbits);

    double s = 0.0;
    for (int i = tid; i < P; i += blockDim.x) {
        u32 v = __float_as_uint(s_mine[i]);
        if (v > tbits) s += (double)s_mine[i];
    }
    const int lane = tid & 63;
    const int wave = tid >> 6;
#pragma unroll
    for (int off = 32; off > 0; off >>= 1) s += __shfl_xor(s, off, 64);
    __shared__ double s_red[8];
    if (lane == 0) s_red[wave] = s;
    __syncthreads();
    if (tid == 0) {
        double t = 0.0;
        for (int w = 0; w < 8; w++) t += s_red[w];
        atomicAdd(&acc[2], t + (double)kr * (double)T);
    }
}

__global__ void k_finalize(const double* __restrict__ acc,
                           const u32* __restrict__ total_pos,
                           float* __restrict__ out) {
    double n = (double)(*total_pos);
    out[0] = (float)(acc[0] / n);
    out[1] = (float)((acc[1] + acc[2]) / n);
}

extern "C" void kernel_launch(void* const* d_in, const int* in_sizes, int n_in,
                              void* d_out, int out_size, void* d_ws, size_t ws_size,
                              hipStream_t stream) {
    const float* loc_preds = (const float*)d_in[0];
    const float* scores    = (const float*)d_in[1];
    const float* gt        = (const float*)d_in[2];
    const float* priors    = (const float*)d_in[3];

    char* ws = (char*)d_ws;
    double* acc      = (double*)ws;
    u32* total_pos   = (u32*)(ws + 24);
    int* num_pos     = (int*)(ws + 32);
    u64* bestkey     = (u64*)(ws + 544);
    float* mine      = (float*)(ws + 16960);

    hipMemsetAsync(d_ws, 0, 16928, stream);

    k_pass1<<<dim3(8, B), dim3(256), 0, stream>>>(gt, priors, bestkey);
    k_pass2<<<dim3((QPI + 255) / 256, B), dim3(256), 0, stream>>>(
        gt, priors, bestkey, loc_preds, scores, mine, num_pos, total_pos, acc);
    k_hardneg<<<dim3(B), dim3(512), 0, stream>>>(mine, num_pos, total_pos, acc);
    k_finalize<<<1, 1, 0, stream>>>(acc, total_pos, (float*)d_out);
}